// Round 1
// 333.305 us; speedup vs baseline: 1.0211x; 1.0211x over previous
//
#include <hip/hip_runtime.h>

// Problem constants
#define NQ     16384       // 4*16*16*16 query vectors
#define EDIM   256
#define NE     8192
#define LHW    4096        // 16*16*16
#define BETA   0.25f

// ws layout (bytes)
#define WS_WSQ    0            // f32[NE]             32768
#define WS_CNT    32768        // u32[NE]             32768
#define WS_LOSS   65536        // f32 (+pad)          256
#define WS_IDX    65792        // u32[NQ]             65536
#define WS_BEST   131328       // u64[NQ] (fallback)  131072
#define WS_APACK  2359552      // ushort[NQ*512]      16777216
#define WS_BPACK  19136768     // ushort[NE*512]      8388608
#define WS_NEED   27525376

typedef __attribute__((ext_vector_type(8))) short bf16x8;
typedef __attribute__((ext_vector_type(4))) float f32x4;

__device__ __forceinline__ unsigned f32_sortable(float f) {
    unsigned b = __float_as_uint(f);
    return b ^ ((unsigned)((int)b >> 31) | 0x80000000u);   // 3 VALU ops
}
__device__ __forceinline__ unsigned short bf16_rn(float f) {
    unsigned u = __float_as_uint(f);
    return (unsigned short)((u + 0x7FFFu + ((u >> 16) & 1u)) >> 16);
}
__device__ __forceinline__ float bf16_tof(unsigned short h) {
    return __uint_as_float(((unsigned)h) << 16);
}

// K1a (MFMA path): wsq + pack_w fused; also zeroes counts/loss (saves 2 memsets).
__global__ __launch_bounds__(256) void wsq_pack_w(const float* __restrict__ w,
                                                  float* __restrict__ wsq,
                                                  unsigned* __restrict__ Bp32,
                                                  unsigned* __restrict__ counts,
                                                  float* __restrict__ loss) {
    int wave = threadIdx.x >> 6, lane = threadIdx.x & 63;
    int row = blockIdx.x * 4 + wave;
    if (blockIdx.x < 32) {
        counts[blockIdx.x * 256 + threadIdx.x] = 0u;
        if (blockIdx.x == 0 && threadIdx.x == 0) loss[0] = 0.f;
    }
    float4 v = *(const float4*)(w + (size_t)row * EDIM + lane * 4);
    double s = (double)v.x * v.x + (double)v.y * v.y +
               (double)v.z * v.z + (double)v.w * v.w;
    unsigned pk[4];
    float vv[4] = {v.x, v.y, v.z, v.w};
    #pragma unroll
    for (int t = 0; t < 4; ++t) {
        unsigned short hi = bf16_rn(vv[t]);
        unsigned short lo = bf16_rn(vv[t] - bf16_tof(hi));
        pk[t] = (unsigned)hi | ((unsigned)lo << 16);
    }
    *(uint4*)(Bp32 + (size_t)row * 256 + lane * 4) = make_uint4(pk[0], pk[1], pk[2], pk[3]);
    #pragma unroll
    for (int off = 32; off; off >>= 1) s += __shfl_xor(s, off, 64);
    if (lane == 0) wsq[row] = (float)s;
}

// K1b (fallback path): wsq only.
__global__ __launch_bounds__(256) void wsq_kernel(const float* __restrict__ w,
                                                  float* __restrict__ wsq) {
    int wave = threadIdx.x >> 6, lane = threadIdx.x & 63;
    int row = blockIdx.x * 4 + wave;
    float4 v = *(const float4*)(w + (size_t)row * EDIM + lane * 4);
    double s = (double)v.x * v.x + (double)v.y * v.y +
               (double)v.z * v.z + (double)v.w * v.w;
    #pragma unroll
    for (int off = 32; off; off >>= 1) s += __shfl_xor(s, off, 64);
    if (lane == 0) wsq[row] = (float)s;
}

// pack_z: z fp32 [4][256][4096] -> Ap bf16 hi/lo ROW-MAJOR [n][512].
__global__ __launch_bounds__(256) void pack_z(const float* __restrict__ z,
                                              unsigned* __restrict__ Ap32) {
    __shared__ unsigned lds[64 * 257];
    int tid = threadIdx.x;
    int tn = tid & 63, tc = tid >> 6;
    int n0 = blockIdx.x * 64;
    int n = n0 + tn;
    int b = n >> 12, lhw = n & 4095;
    for (int cc = 0; cc < 64; ++cc) {
        int d = tc * 64 + cc;
        float v = z[((size_t)b * EDIM + d) * LHW + lhw];
        unsigned short hi = bf16_rn(v);
        unsigned short lo = bf16_rn(v - bf16_tof(hi));
        lds[tn * 257 + d] = (unsigned)hi | ((unsigned)lo << 16);
    }
    __syncthreads();
    for (int p = 0; p < 64; ++p) {
        int flat = p * 256 + tid;
        int row = flat >> 8, cl = flat & 255;
        Ap32[(size_t)(n0 + row) * 256 + cl] = lds[row * 257 + cl];
    }
}

// K2-MFMA v10: same math/tile as v9 (wave 64n x 128e, r10 XOR swizzle, 0
// conflicts) but the K-loop is re-scheduled as a double-buffered pipeline
// (T3+T4+T5 from the technique catalog):
//   - LDS B is 2 x 16 KB; chunk k+1's global_load_lds issues BEFORE chunk k's
//     MFMAs, so its L2/L3 latency hides under ~64 MFMAs of compute.
//   - raw s_barrier + counted s_waitcnt vmcnt(12) replaces __syncthreads'
//     vmcnt(0) drain: per thread, issue order is af(8) then glds(4), so the
//     current buffer's glds (issued last iter) have exactly 12 newer vmem ops.
//     Last chunk has no prefetch -> vmcnt(8).
//   - memory-clobber asm fences bracket each barrier and separate af-loads
//     from STAGE so the compiler can't migrate vmem ops across the counts.
//   - s_setprio(1) around the MFMA cluster (pays once phases are split).
// v9 measured 205 µs @ MfmaUtil 28% (two serial full-latency drains/chunk);
// predicted ~115-140 µs @ 45-55%.
__global__ __launch_bounds__(256, 2) void dist_mfma(const unsigned short* __restrict__ Ap,
                                                    const unsigned short* __restrict__ Bp,
                                                    const float* __restrict__ wsq,
                                                    unsigned* __restrict__ s1) {
    __shared__ __align__(16) unsigned short lds_b[2][128 * 64];   // 2 x 16 KB, swizzled
    int tid = threadIdx.x, lane = tid & 63, w = tid >> 6;
    int x = blockIdx.x, nt = blockIdx.y;
    int quad = lane >> 4, col = lane & 15;
    int rsel = lane >> 3, seg = lane & 7;   // glds: 8 rows x 8 segs of 16B per call

    const unsigned short* arow = Ap + (size_t)(nt * 256 + w * 64 + col) * 512;
    const unsigned short* Bbase = Bp + (size_t)(x * 128) * 512;

    f32x4 acc[4][8];
    #pragma unroll
    for (int i = 0; i < 4; ++i)
        #pragma unroll
        for (int j = 0; j < 8; ++j) acc[i][j] = (f32x4){0.f, 0.f, 0.f, 0.f};

    // stage B chunk kc into lds_b[bsel]: 16 calls of 1KB (4/wave), r10 swizzle.
    auto stage_chunk = [&](int kc, int bsel) {
        int k0s = kc * 64;
        #pragma unroll
        for (int p = 0; p < 4; ++p) {
            int c = w * 4 + p;
            const unsigned short* gb =
                Bbase + (size_t)(c * 8 + rsel) * 512 + k0s + ((seg ^ (rsel & 7)) * 8);
            __builtin_amdgcn_global_load_lds(
                (const __attribute__((address_space(1))) void*)gb,
                (__attribute__((address_space(3))) void*)(&lds_b[bsel][c * 512]),
                16, 0, 0);
        }
    };

    // prologue: stage chunk 0 into buffer 0 (no barrier needed; LDS unread yet)
    stage_chunk(0, 0);

    #pragma unroll
    for (int kcc = 0; kcc < 8; ++kcc) {
        int k0 = kcc * 64;
        int cur = kcc & 1;
        // A frags for this chunk: global -> VGPR (L2-resident tile). Issued
        // BEFORE the next-chunk glds so the compiler's pre-MFMA wait for af
        // is vmcnt(4) (leaves the 4 prefetch glds in flight), not vmcnt(0).
        bf16x8 af[4][2];
        #pragma unroll
        for (int i = 0; i < 4; ++i)
            #pragma unroll
            for (int h = 0; h < 2; ++h)
                af[i][h] = *(const bf16x8*)(arow + i * 16 * 512 + k0 + h * 32 + quad * 8);
        asm volatile("" ::: "memory");   // af above / glds below: fixes issue order
        if (kcc < 7) {
            stage_chunk(kcc + 1, cur ^ 1);
            // wait for MY glds of the CURRENT buffer (issued last iter):
            // newer vmem ops = af(8) + glds_next(4) = 12 (in-order retirement).
            asm volatile("s_waitcnt vmcnt(12)" ::: "memory");
        } else {
            // no prefetch issued: newer ops = af(8) only.
            asm volatile("s_waitcnt vmcnt(8)" ::: "memory");
        }
        __builtin_amdgcn_s_barrier();    // all waves' glds for cur buffer done
        asm volatile("" ::: "memory");   // ds_reads must not hoist above barrier
        __builtin_amdgcn_s_setprio(1);
        #pragma unroll
        for (int h = 0; h < 2; ++h) {
            bf16x8 bf[8];
            #pragma unroll
            for (int j = 0; j < 8; ++j)
                bf[j] = *(const bf16x8*)(&lds_b[cur][(j * 16 + col) * 64 +
                                         (((h * 4 + quad) ^ (col & 7)) * 8)]);
            #pragma unroll
            for (int i = 0; i < 4; ++i)
                #pragma unroll
                for (int j = 0; j < 8; ++j)
                    acc[i][j] = __builtin_amdgcn_mfma_f32_16x16x32_bf16(
                        af[i][h], bf[j], acc[i][j], 0, 0, 0);
        }
        __builtin_amdgcn_s_setprio(0);
        asm volatile("" ::: "memory");   // ds_reads/MFMA stay above the barrier
        if (kcc < 7) {
            // all waves done reading lds_b[cur] before next iter's glds
            // overwrite it (next iter stages chunk kcc+2 into buffer cur).
            __builtin_amdgcn_s_barrier();
            asm volatile("" ::: "memory");   // next glds must not hoist above
        }
    }

    // epilogue: d = wsq[e] - 2*dot; u32 key = trunc-sortable(d) | e_local;
    // branchless top-2 per (i,r), then cross-lane merge over 16 e-lanes.
    unsigned m1[4][4], m2[4][4];
    #pragma unroll
    for (int i = 0; i < 4; ++i)
        #pragma unroll
        for (int r = 0; r < 4; ++r) { m1[i][r] = 0xFFFFFFFFu; m2[i][r] = 0xFFFFFFFFu; }
    #pragma unroll
    for (int j = 0; j < 8; ++j) {
        int e = x * 128 + j * 16 + col;
        unsigned jc = (unsigned)(j * 16 + col);   // e_local, 7 bits
        float wq = wsq[e];
        #pragma unroll
        for (int i = 0; i < 4; ++i)
            #pragma unroll
            for (int r = 0; r < 4; ++r) {
                float d = fmaf(-2.0f, acc[i][j][r], wq);
                unsigned k = (f32_sortable(d) & 0xFFFFFF80u) | jc;
                unsigned mx = (m1[i][r] > k) ? m1[i][r] : k;
                m1[i][r] = (m1[i][r] < k) ? m1[i][r] : k;
                m2[i][r] = (m2[i][r] < mx) ? m2[i][r] : mx;
            }
    }
    #pragma unroll
    for (int i = 0; i < 4; ++i)
        #pragma unroll
        for (int r = 0; r < 4; ++r) {
            unsigned a1 = m1[i][r], a2 = m2[i][r];
            #pragma unroll
            for (int off = 1; off < 16; off <<= 1) {
                unsigned b1 = __shfl_xor(a1, off, 64);
                unsigned b2 = __shfl_xor(a2, off, 64);
                unsigned lo1 = a1 < b1 ? a1 : b1;
                unsigned hi1 = a1 < b1 ? b1 : a1;
                unsigned lo2 = a2 < b2 ? a2 : b2;
                a1 = lo1;
                a2 = hi1 < lo2 ? hi1 : lo2;
            }
            if (col == 0) {
                int q = nt * 256 + w * 64 + i * 16 + quad * 4 + r;
                size_t o = (size_t)q * 128 + x * 2;
                s1[o] = a1; s1[o + 1] = a2;
            }
        }
}

// Refine (merge fused): per query, lane=slice holds its top-2 u32 keys;
// 3-step shfl-xor top-2 reduce within 8-lane groups -> 16 candidates
// (top-2 per 1024-e group); then exact fp32 distance for all 16,
// true argmin with first-index tiebreak. One wave per query.
__global__ __launch_bounds__(256) void refine_kernel(const float* __restrict__ z,
                                                     const float* __restrict__ w,
                                                     const float* __restrict__ wsq,
                                                     const unsigned* __restrict__ s1,
                                                     unsigned* __restrict__ idxarr) {
    int tid = threadIdx.x, lane = tid & 63, wv = tid >> 6;
    int q = blockIdx.x * 4 + wv;
    int b = q >> 12, lhw = q & 4095;
    // slice keys -> global u64 keys: (d_trunc << 13) | e_global
    uint2 kk2 = *(const uint2*)(s1 + (size_t)q * 128 + lane * 2);
    unsigned long long a1 =
        ((unsigned long long)(kk2.x >> 7) << 13) | (unsigned)(lane * 128 + (kk2.x & 127u));
    unsigned long long a2 =
        ((unsigned long long)(kk2.y >> 7) << 13) | (unsigned)(lane * 128 + (kk2.y & 127u));
    #pragma unroll
    for (int off = 1; off < 8; off <<= 1) {
        unsigned long long b1 = __shfl_xor(a1, off, 64);
        unsigned long long b2 = __shfl_xor(a2, off, 64);
        unsigned long long lo1 = a1 < b1 ? a1 : b1;
        unsigned long long hi1 = a1 < b1 ? b1 : a1;
        unsigned long long lo2 = a2 < b2 ? a2 : b2;
        a1 = lo1;
        a2 = hi1 < lo2 ? hi1 : lo2;
    }
    float zv[4];
    #pragma unroll
    for (int t = 0; t < 4; ++t)
        zv[t] = z[((size_t)b * EDIM + lane * 4 + t) * LHW + lhw];
    unsigned long long bestk = ~0ull;
    #pragma unroll
    for (int c = 0; c < 16; ++c) {
        int src = (c >> 1) * 8;
        unsigned long long kc = (c & 1) ? __shfl(a2, src, 64) : __shfl(a1, src, 64);
        unsigned e = (unsigned)(kc & (unsigned long long)(NE - 1));
        float4 wv4 = *(const float4*)(w + (size_t)e * EDIM + lane * 4);
        float p = zv[0] * wv4.x + zv[1] * wv4.y + zv[2] * wv4.z + zv[3] * wv4.w;
        #pragma unroll
        for (int off = 32; off; off >>= 1) p += __shfl_xor(p, off, 64);
        float d = wsq[e] - 2.0f * p;
        unsigned long long key = ((unsigned long long)f32_sortable(d) << 32) | e;
        if (key < bestk) bestk = key;
    }
    if (lane == 0) idxarr[q] = (unsigned)(bestk & 0xFFFFFFFFull);
}

// ---------- fallback fp32 path (used when ws_size < WS_NEED) ----------
__global__ __launch_bounds__(256, 2) void dist_fp32(const float* __restrict__ z,
                                                    const float* __restrict__ w,
                                                    const float* __restrict__ wsq,
                                                    unsigned long long* __restrict__ best) {
    __shared__ float lds_a[32 * 128];
    __shared__ float lds_b[32 * 132];
    int tid = threadIdx.x;
    int tx = tid & 15, ty = tid >> 4;
    int n0 = blockIdx.y * 128;
    int bb_ = n0 >> 12, lhw0 = n0 & 4095;
    const float* zb = z + (size_t)bb_ * (EDIM * LHW) + lhw0;
    int ebase = blockIdx.x * 2048;
    unsigned long long runmin[8];
    #pragma unroll
    for (int i = 0; i < 8; ++i) runmin[i] = ~0ull;
    float acc[64];
    for (int et = 0; et < 16; ++et) {
        int e0 = ebase + et * 128;
        #pragma unroll
        for (int i = 0; i < 64; ++i) acc[i] = 0.f;
        for (int kc = 0; kc < 8; ++kc) {
            int k0 = kc * 32;
            #pragma unroll
            for (int p = 0; p < 4; ++p) {
                int f = p * 256 + tid;
                int kk = f >> 5, nn4 = f & 31;
                float4 v = *(const float4*)(zb + (size_t)(k0 + kk) * LHW + nn4 * 4);
                *((float4*)(lds_a + kk * 128 + nn4 * 4)) = v;
            }
            #pragma unroll
            for (int p = 0; p < 4; ++p) {
                int f = p * 256 + tid;
                int ee = f >> 3, kk4 = f & 7;
                float4 v = *(const float4*)(w + (size_t)(e0 + ee) * EDIM + k0 + kk4 * 4);
                lds_b[(kk4 * 4 + 0) * 132 + ee] = v.x;
                lds_b[(kk4 * 4 + 1) * 132 + ee] = v.y;
                lds_b[(kk4 * 4 + 2) * 132 + ee] = v.z;
                lds_b[(kk4 * 4 + 3) * 132 + ee] = v.w;
            }
            __syncthreads();
            #pragma unroll
            for (int k = 0; k < 32; ++k) {
                float a[8], bv[8];
                *(float4*)(a)      = *(float4*)(lds_a + k * 128 + ty * 8);
                *(float4*)(a + 4)  = *(float4*)(lds_a + k * 128 + ty * 8 + 4);
                *(float4*)(bv)     = *(float4*)(lds_b + k * 132 + tx * 8);
                *(float4*)(bv + 4) = *(float4*)(lds_b + k * 132 + tx * 8 + 4);
                #pragma unroll
                for (int i = 0; i < 8; ++i)
                    #pragma unroll
                    for (int j = 0; j < 8; ++j)
                        acc[i * 8 + j] = fmaf(a[i], bv[j], acc[i * 8 + j]);
            }
            __syncthreads();
        }
        #pragma unroll
        for (int i = 0; i < 8; ++i) {
            unsigned long long m = runmin[i];
            #pragma unroll
            for (int j = 0; j < 8; ++j) {
                int e = e0 + tx * 8 + j;
                float d = wsq[e] - 2.0f * acc[i * 8 + j];
                unsigned long long key =
                    ((unsigned long long)f32_sortable(d) << 32) | (unsigned)e;
                m = (m < key) ? m : key;
            }
            runmin[i] = m;
        }
    }
    #pragma unroll
    for (int i = 0; i < 8; ++i) {
        unsigned long long kk = runmin[i];
        #pragma unroll
        for (int off = 8; off >= 1; off >>= 1) {
            unsigned long long o = __shfl_xor(kk, off, 16);
            kk = (kk < o) ? kk : o;
        }
        if (tx == 0) atomicMin(&best[n0 + ty * 8 + i], kk);
    }
}

__global__ __launch_bounds__(256) void extract_idx(const unsigned long long* __restrict__ best,
                                                   unsigned* __restrict__ idxarr) {
    int n = blockIdx.x * 256 + threadIdx.x;
    idxarr[n] = (unsigned)(best[n] & 0xFFFFFFFFull) & (NE - 1);
}

// K3: gather codebook rows, transpose-write z_q_st, loss partials, histogram, idx out.
__global__ __launch_bounds__(256) void gather_kernel(const float* __restrict__ z,
                                                     const float* __restrict__ w,
                                                     const unsigned* __restrict__ idxarr,
                                                     unsigned* __restrict__ counts,
                                                     float* __restrict__ loss,
                                                     float* __restrict__ out,
                                                     float* __restrict__ out_idx) {
    __shared__ int idx_s[64];
    __shared__ float wl[64 * 257];
    int tid = threadIdx.x;
    int n0 = blockIdx.x * 64;
    if (tid < 64) {
        int idx = (int)(idxarr[n0 + tid] & (NE - 1));
        idx_s[tid] = idx;
        out_idx[n0 + tid] = (float)idx;
        atomicAdd(&counts[idx], 1u);
    }
    __syncthreads();
    for (int i = 0; i < 64; ++i)
        wl[i * 257 + tid] = w[(size_t)idx_s[i] * EDIM + tid];
    __syncthreads();
    int tn = tid & 63, tc = tid >> 6;
    int bb_ = n0 >> 12, lhw0 = n0 & 4095;
    size_t zb = (size_t)bb_ * (EDIM * LHW) + lhw0 + tn;
    float accl = 0.f;
    for (int cc = 0; cc < 64; ++cc) {
        int c = tc * 64 + cc;
        float wv = wl[tn * 257 + c];
        size_t a = zb + (size_t)c * LHW;
        float zv = z[a];
        float diff = wv - zv;            // z_q - zc
        out[a] = zv + diff;              // replicate zc + (z_q - zc) rounding
        accl += diff * diff;
    }
    #pragma unroll
    for (int off = 32; off; off >>= 1) accl += __shfl_xor(accl, off, 64);
    if ((tid & 63) == 0) atomicAdd(loss, accl);
}

// K4: scalars
__global__ __launch_bounds__(256) void finalize_kernel(const unsigned* __restrict__ counts,
                                                       const float* __restrict__ loss,
                                                       float* __restrict__ out_scalars) {
    __shared__ float ss[4];
    __shared__ int uu[4];
    int tid = threadIdx.x;
    float s = 0.f;
    int uniq = 0;
    for (int i = tid; i < NE; i += 256) {
        unsigned c = counts[i];
        if (c > 0) {
            float p = (float)c * (1.0f / (float)NQ);
            s += p * logf(p + 1e-10f);
            uniq++;
        }
    }
    #pragma unroll
    for (int off = 32; off; off >>= 1) {
        s += __shfl_xor(s, off, 64);
        uniq += __shfl_xor(uniq, off, 64);
    }
    int wave = tid >> 6;
    if ((tid & 63) == 0) { ss[wave] = s; uu[wave] = uniq; }
    __syncthreads();
    if (tid == 0) {
        float st = ss[0] + ss[1] + ss[2] + ss[3];
        int ut = uu[0] + uu[1] + uu[2] + uu[3];
        out_scalars[0] = BETA * loss[0] * (1.0f / (float)(NQ * EDIM));  // loss
        out_scalars[1] = expf(-st);                                     // perplexity
        out_scalars[2] = (float)ut;                                     // unique
    }
}

extern "C" void kernel_launch(void* const* d_in, const int* in_sizes, int n_in,
                              void* d_out, int out_size, void* d_ws, size_t ws_size,
                              hipStream_t stream) {
    const float* z = (const float*)d_in[0];
    const float* w = (const float*)d_in[1];
    float* out = (float*)d_out;
    char* ws = (char*)d_ws;
    float* wsq = (float*)(ws + WS_WSQ);
    unsigned* counts = (unsigned*)(ws + WS_CNT);
    float* loss = (float*)(ws + WS_LOSS);
    unsigned* idxarr = (unsigned*)(ws + WS_IDX);
    unsigned long long* best = (unsigned long long*)(ws + WS_BEST);
    unsigned* Ap = (unsigned*)(ws + WS_APACK);
    unsigned* Bp = (unsigned*)(ws + WS_BPACK);

    int idx_off = out_size - NQ;
    int scal_off = idx_off - 3;
    float* out_idx = out + idx_off;
    float* out_scalars = out + scal_off;

    // z_q region of d_out doubles as the per-slice top-2 scratch (u32 keys,
    // written by dist_mfma, read by refine, overwritten by gather).
    unsigned* s1 = (unsigned*)out;

    if (ws_size >= (size_t)WS_NEED) {
        wsq_pack_w<<<NE / 4, 256, 0, stream>>>(w, wsq, Bp, counts, loss);
        pack_z<<<NQ / 64, 256, 0, stream>>>(z, Ap);
        dist_mfma<<<dim3(64, 64), 256, 0, stream>>>((const unsigned short*)Ap,
                                                    (const unsigned short*)Bp, wsq, s1);
        refine_kernel<<<NQ / 4, 256, 0, stream>>>(z, w, wsq, s1, idxarr);
    } else {
        hipMemsetAsync(counts, 0, NE * sizeof(unsigned), stream);
        hipMemsetAsync(loss, 0, sizeof(float), stream);
        wsq_kernel<<<NE / 4, 256, 0, stream>>>(w, wsq);
        hipMemsetAsync(best, 0xFF, NQ * sizeof(unsigned long long), stream);
        dist_fp32<<<dim3(4, 128), 256, 0, stream>>>(z, w, wsq, best);
        extract_idx<<<NQ / 256, 256, 0, stream>>>(best, idxarr);
    }

    gather_kernel<<<NQ / 64, 256, 0, stream>>>(z, w, idxarr, counts, loss, out, out_idx);
    finalize_kernel<<<1, 256, 0, stream>>>(counts, loss, out_scalars);
}

// Round 2
// 260.906 us; speedup vs baseline: 1.3045x; 1.2775x over previous
//
#include <hip/hip_runtime.h>

// Problem constants
#define NQ     16384       // 4*16*16*16 query vectors
#define EDIM   256
#define NE     8192
#define LHW    4096        // 16*16*16
#define BETA   0.25f

// ws layout (bytes) — K=256 bf16-hi packing (lo channel dropped: it only
// contributed the ~2^-16 alo*blo diagonal term; the cross terms were never
// computed by the interleaved layout, and the epilogue key truncation is
// ~8e-3 — two orders coarser).
#define WS_WSQ    0            // f32[NE]             32768
#define WS_CNT    32768        // u32[NE]             32768
#define WS_LOSS   65536        // f32 (+pad)          256
#define WS_IDX    65792        // u32[NQ]             65536
#define WS_BEST   131328       // u64[NQ] (fallback)  131072
#define WS_APACK  2359552      // ushort[NQ*256]      8388608
#define WS_BPACK  10748160     // ushort[NE*256]      4194304
#define WS_NEED   14942464

typedef __attribute__((ext_vector_type(8))) short bf16x8;
typedef __attribute__((ext_vector_type(4))) float f32x4;

__device__ __forceinline__ unsigned f32_sortable(float f) {
    unsigned b = __float_as_uint(f);
    return b ^ ((unsigned)((int)b >> 31) | 0x80000000u);   // 3 VALU ops
}
__device__ __forceinline__ unsigned short bf16_rn(float f) {
    unsigned u = __float_as_uint(f);
    return (unsigned short)((u + 0x7FFFu + ((u >> 16) & 1u)) >> 16);
}

// K1a (MFMA path): wsq + pack_w (bf16-hi only) fused; zeroes counts/loss.
__global__ __launch_bounds__(256) void wsq_pack_w(const float* __restrict__ w,
                                                  float* __restrict__ wsq,
                                                  unsigned* __restrict__ Bp32,
                                                  unsigned* __restrict__ counts,
                                                  float* __restrict__ loss) {
    int wave = threadIdx.x >> 6, lane = threadIdx.x & 63;
    int row = blockIdx.x * 4 + wave;
    if (blockIdx.x < 32) {
        counts[blockIdx.x * 256 + threadIdx.x] = 0u;
        if (blockIdx.x == 0 && threadIdx.x == 0) loss[0] = 0.f;
    }
    float4 v = *(const float4*)(w + (size_t)row * EDIM + lane * 4);
    double s = (double)v.x * v.x + (double)v.y * v.y +
               (double)v.z * v.z + (double)v.w * v.w;
    unsigned p0 = (unsigned)bf16_rn(v.x) | ((unsigned)bf16_rn(v.y) << 16);
    unsigned p1 = (unsigned)bf16_rn(v.z) | ((unsigned)bf16_rn(v.w) << 16);
    *(uint2*)(Bp32 + (size_t)row * 128 + lane * 2) = make_uint2(p0, p1);
    #pragma unroll
    for (int off = 32; off; off >>= 1) s += __shfl_xor(s, off, 64);
    if (lane == 0) wsq[row] = (float)s;
}

// K1b (fallback path): wsq only.
__global__ __launch_bounds__(256) void wsq_kernel(const float* __restrict__ w,
                                                  float* __restrict__ wsq) {
    int wave = threadIdx.x >> 6, lane = threadIdx.x & 63;
    int row = blockIdx.x * 4 + wave;
    float4 v = *(const float4*)(w + (size_t)row * EDIM + lane * 4);
    double s = (double)v.x * v.x + (double)v.y * v.y +
               (double)v.z * v.z + (double)v.w * v.w;
    #pragma unroll
    for (int off = 32; off; off >>= 1) s += __shfl_xor(s, off, 64);
    if (lane == 0) wsq[row] = (float)s;
}

// pack_z: z fp32 [4][256][4096] -> Ap bf16-hi ROW-MAJOR [n][256].
// Pairs of dims packed into u32 in LDS; stride 129 u32 (=516B, bank+1) -> no
// conflicts on either phase.
__global__ __launch_bounds__(256) void pack_z(const float* __restrict__ z,
                                              unsigned* __restrict__ Ap32) {
    __shared__ unsigned lds[64 * 129];
    int tid = threadIdx.x;
    int tn = tid & 63, tc = tid >> 6;
    int n0 = blockIdx.x * 64;
    int n = n0 + tn;
    int b = n >> 12, lhw = n & 4095;
    for (int cc = 0; cc < 64; cc += 2) {
        int d = tc * 64 + cc;
        float v0 = z[((size_t)b * EDIM + d) * LHW + lhw];
        float v1 = z[((size_t)b * EDIM + d + 1) * LHW + lhw];
        lds[tn * 129 + (d >> 1)] =
            (unsigned)bf16_rn(v0) | ((unsigned)bf16_rn(v1) << 16);
    }
    __syncthreads();
    for (int p = 0; p < 32; ++p) {
        int flat = p * 256 + tid;           // 64 rows x 128 u32
        int row = flat >> 7, c = flat & 127;
        Ap32[(size_t)(n0 + row) * 128 + c] = lds[row * 129 + c];
    }
}

// K2-MFMA v11: identical per-chunk geometry to v10 (wave 64n x 128e, BK=64,
// r10 XOR swizzle, 0 conflicts, double-buffered LDS, counted vmcnt, setprio)
// but K=256 (bf16-hi only) -> 4 chunks instead of 8. Global row stride is now
// 256 ushorts; LDS layout and all swizzles unchanged.
__global__ __launch_bounds__(256, 2) void dist_mfma(const unsigned short* __restrict__ Ap,
                                                    const unsigned short* __restrict__ Bp,
                                                    const float* __restrict__ wsq,
                                                    unsigned* __restrict__ s1) {
    __shared__ __align__(16) unsigned short lds_b[2][128 * 64];   // 2 x 16 KB, swizzled
    int tid = threadIdx.x, lane = tid & 63, w = tid >> 6;
    int x = blockIdx.x, nt = blockIdx.y;
    int quad = lane >> 4, col = lane & 15;
    int rsel = lane >> 3, seg = lane & 7;   // glds: 8 rows x 8 segs of 16B per call

    const unsigned short* arow = Ap + (size_t)(nt * 256 + w * 64 + col) * 256;
    const unsigned short* Bbase = Bp + (size_t)(x * 128) * 256;

    f32x4 acc[4][8];
    #pragma unroll
    for (int i = 0; i < 4; ++i)
        #pragma unroll
        for (int j = 0; j < 8; ++j) acc[i][j] = (f32x4){0.f, 0.f, 0.f, 0.f};

    // stage B chunk kc into lds_b[bsel]: 16 calls of 1KB (4/wave), r10 swizzle.
    auto stage_chunk = [&](int kc, int bsel) {
        int k0s = kc * 64;
        #pragma unroll
        for (int p = 0; p < 4; ++p) {
            int c = w * 4 + p;
            const unsigned short* gb =
                Bbase + (size_t)(c * 8 + rsel) * 256 + k0s + ((seg ^ (rsel & 7)) * 8);
            __builtin_amdgcn_global_load_lds(
                (const __attribute__((address_space(1))) void*)gb,
                (__attribute__((address_space(3))) void*)(&lds_b[bsel][c * 512]),
                16, 0, 0);
        }
    };

    // prologue: stage chunk 0 into buffer 0 (no barrier needed; LDS unread yet)
    stage_chunk(0, 0);

    #pragma unroll
    for (int kcc = 0; kcc < 4; ++kcc) {
        int k0 = kcc * 64;
        int cur = kcc & 1;
        // A frags for this chunk: global -> VGPR (L2-resident tile), issued
        // before the next-chunk glds.
        bf16x8 af[4][2];
        #pragma unroll
        for (int i = 0; i < 4; ++i)
            #pragma unroll
            for (int h = 0; h < 2; ++h)
                af[i][h] = *(const bf16x8*)(arow + i * 16 * 256 + k0 + h * 32 + quad * 8);
        asm volatile("" ::: "memory");   // af above / glds below: fixes issue order
        if (kcc < 3) {
            stage_chunk(kcc + 1, cur ^ 1);
            // wait for MY glds of the CURRENT buffer (issued last iter):
            // newer vmem ops = af(8) + glds_next(4) = 12 (in-order retirement).
            asm volatile("s_waitcnt vmcnt(12)" ::: "memory");
        } else {
            // no prefetch issued: newer ops = af(8) only.
            asm volatile("s_waitcnt vmcnt(8)" ::: "memory");
        }
        __builtin_amdgcn_s_barrier();    // all waves' glds for cur buffer done
        asm volatile("" ::: "memory");   // ds_reads must not hoist above barrier
        __builtin_amdgcn_s_setprio(1);
        #pragma unroll
        for (int h = 0; h < 2; ++h) {
            bf16x8 bf[8];
            #pragma unroll
            for (int j = 0; j < 8; ++j)
                bf[j] = *(const bf16x8*)(&lds_b[cur][(j * 16 + col) * 64 +
                                         (((h * 4 + quad) ^ (col & 7)) * 8)]);
            #pragma unroll
            for (int i = 0; i < 4; ++i)
                #pragma unroll
                for (int j = 0; j < 8; ++j)
                    acc[i][j] = __builtin_amdgcn_mfma_f32_16x16x32_bf16(
                        af[i][h], bf[j], acc[i][j], 0, 0, 0);
        }
        __builtin_amdgcn_s_setprio(0);
        asm volatile("" ::: "memory");   // ds_reads/MFMA stay above the barrier
        if (kcc < 3) {
            // all waves done reading lds_b[cur] before next iter's glds
            // overwrite it (next iter stages chunk kcc+2 into buffer cur).
            __builtin_amdgcn_s_barrier();
            asm volatile("" ::: "memory");   // next glds must not hoist above
        }
    }

    // epilogue: d = wsq[e] - 2*dot; u32 key = trunc-sortable(d) | e_local;
    // branchless top-2 per (i,r), then cross-lane merge over 16 e-lanes.
    unsigned m1[4][4], m2[4][4];
    #pragma unroll
    for (int i = 0; i < 4; ++i)
        #pragma unroll
        for (int r = 0; r < 4; ++r) { m1[i][r] = 0xFFFFFFFFu; m2[i][r] = 0xFFFFFFFFu; }
    #pragma unroll
    for (int j = 0; j < 8; ++j) {
        int e = x * 128 + j * 16 + col;
        unsigned jc = (unsigned)(j * 16 + col);   // e_local, 7 bits
        float wq = wsq[e];
        #pragma unroll
        for (int i = 0; i < 4; ++i)
            #pragma unroll
            for (int r = 0; r < 4; ++r) {
                float d = fmaf(-2.0f, acc[i][j][r], wq);
                unsigned k = (f32_sortable(d) & 0xFFFFFF80u) | jc;
                unsigned mx = (m1[i][r] > k) ? m1[i][r] : k;
                m1[i][r] = (m1[i][r] < k) ? m1[i][r] : k;
                m2[i][r] = (m2[i][r] < mx) ? m2[i][r] : mx;
            }
    }
    #pragma unroll
    for (int i = 0; i < 4; ++i)
        #pragma unroll
        for (int r = 0; r < 4; ++r) {
            unsigned a1 = m1[i][r], a2 = m2[i][r];
            #pragma unroll
            for (int off = 1; off < 16; off <<= 1) {
                unsigned b1 = __shfl_xor(a1, off, 64);
                unsigned b2 = __shfl_xor(a2, off, 64);
                unsigned lo1 = a1 < b1 ? a1 : b1;
                unsigned hi1 = a1 < b1 ? b1 : a1;
                unsigned lo2 = a2 < b2 ? a2 : b2;
                a1 = lo1;
                a2 = hi1 < lo2 ? hi1 : lo2;
            }
            if (col == 0) {
                int q = nt * 256 + w * 64 + i * 16 + quad * 4 + r;
                size_t o = (size_t)q * 128 + x * 2;
                s1[o] = a1; s1[o + 1] = a2;
            }
        }
}

// Refine (merge fused): per query, lane=slice holds its top-2 u32 keys;
// 3-step shfl-xor top-2 reduce within 8-lane groups -> 16 candidates
// (top-2 per 1024-e group); then exact fp32 distance for all 16,
// true argmin with first-index tiebreak. One wave per query.
__global__ __launch_bounds__(256) void refine_kernel(const float* __restrict__ z,
                                                     const float* __restrict__ w,
                                                     const float* __restrict__ wsq,
                                                     const unsigned* __restrict__ s1,
                                                     unsigned* __restrict__ idxarr) {
    int tid = threadIdx.x, lane = tid & 63, wv = tid >> 6;
    int q = blockIdx.x * 4 + wv;
    int b = q >> 12, lhw = q & 4095;
    // slice keys -> global u64 keys: (d_trunc << 13) | e_global
    uint2 kk2 = *(const uint2*)(s1 + (size_t)q * 128 + lane * 2);
    unsigned long long a1 =
        ((unsigned long long)(kk2.x >> 7) << 13) | (unsigned)(lane * 128 + (kk2.x & 127u));
    unsigned long long a2 =
        ((unsigned long long)(kk2.y >> 7) << 13) | (unsigned)(lane * 128 + (kk2.y & 127u));
    #pragma unroll
    for (int off = 1; off < 8; off <<= 1) {
        unsigned long long b1 = __shfl_xor(a1, off, 64);
        unsigned long long b2 = __shfl_xor(a2, off, 64);
        unsigned long long lo1 = a1 < b1 ? a1 : b1;
        unsigned long long hi1 = a1 < b1 ? b1 : a1;
        unsigned long long lo2 = a2 < b2 ? a2 : b2;
        a1 = lo1;
        a2 = hi1 < lo2 ? hi1 : lo2;
    }
    float zv[4];
    #pragma unroll
    for (int t = 0; t < 4; ++t)
        zv[t] = z[((size_t)b * EDIM + lane * 4 + t) * LHW + lhw];
    unsigned long long bestk = ~0ull;
    #pragma unroll
    for (int c = 0; c < 16; ++c) {
        int src = (c >> 1) * 8;
        unsigned long long kc = (c & 1) ? __shfl(a2, src, 64) : __shfl(a1, src, 64);
        unsigned e = (unsigned)(kc & (unsigned long long)(NE - 1));
        float4 wv4 = *(const float4*)(w + (size_t)e * EDIM + lane * 4);
        float p = zv[0] * wv4.x + zv[1] * wv4.y + zv[2] * wv4.z + zv[3] * wv4.w;
        #pragma unroll
        for (int off = 32; off; off >>= 1) p += __shfl_xor(p, off, 64);
        float d = wsq[e] - 2.0f * p;
        unsigned long long key = ((unsigned long long)f32_sortable(d) << 32) | e;
        if (key < bestk) bestk = key;
    }
    if (lane == 0) idxarr[q] = (unsigned)(bestk & 0xFFFFFFFFull);
}

// ---------- fallback fp32 path (used when ws_size < WS_NEED) ----------
__global__ __launch_bounds__(256, 2) void dist_fp32(const float* __restrict__ z,
                                                    const float* __restrict__ w,
                                                    const float* __restrict__ wsq,
                                                    unsigned long long* __restrict__ best) {
    __shared__ float lds_a[32 * 128];
    __shared__ float lds_b[32 * 132];
    int tid = threadIdx.x;
    int tx = tid & 15, ty = tid >> 4;
    int n0 = blockIdx.y * 128;
    int bb_ = n0 >> 12, lhw0 = n0 & 4095;
    const float* zb = z + (size_t)bb_ * (EDIM * LHW) + lhw0;
    int ebase = blockIdx.x * 2048;
    unsigned long long runmin[8];
    #pragma unroll
    for (int i = 0; i < 8; ++i) runmin[i] = ~0ull;
    float acc[64];
    for (int et = 0; et < 16; ++et) {
        int e0 = ebase + et * 128;
        #pragma unroll
        for (int i = 0; i < 64; ++i) acc[i] = 0.f;
        for (int kc = 0; kc < 8; ++kc) {
            int k0 = kc * 32;
            #pragma unroll
            for (int p = 0; p < 4; ++p) {
                int f = p * 256 + tid;
                int kk = f >> 5, nn4 = f & 31;
                float4 v = *(const float4*)(zb + (size_t)(k0 + kk) * LHW + nn4 * 4);
                *((float4*)(lds_a + kk * 128 + nn4 * 4)) = v;
            }
            #pragma unroll
            for (int p = 0; p < 4; ++p) {
                int f = p * 256 + tid;
                int ee = f >> 3, kk4 = f & 7;
                float4 v = *(const float4*)(w + (size_t)(e0 + ee) * EDIM + k0 + kk4 * 4);
                lds_b[(kk4 * 4 + 0) * 132 + ee] = v.x;
                lds_b[(kk4 * 4 + 1) * 132 + ee] = v.y;
                lds_b[(kk4 * 4 + 2) * 132 + ee] = v.z;
                lds_b[(kk4 * 4 + 3) * 132 + ee] = v.w;
            }
            __syncthreads();
            #pragma unroll
            for (int k = 0; k < 32; ++k) {
                float a[8], bv[8];
                *(float4*)(a)      = *(float4*)(lds_a + k * 128 + ty * 8);
                *(float4*)(a + 4)  = *(float4*)(lds_a + k * 128 + ty * 8 + 4);
                *(float4*)(bv)     = *(float4*)(lds_b + k * 132 + tx * 8);
                *(float4*)(bv + 4) = *(float4*)(lds_b + k * 132 + tx * 8 + 4);
                #pragma unroll
                for (int i = 0; i < 8; ++i)
                    #pragma unroll
                    for (int j = 0; j < 8; ++j)
                        acc[i * 8 + j] = fmaf(a[i], bv[j], acc[i * 8 + j]);
            }
            __syncthreads();
        }
        #pragma unroll
        for (int i = 0; i < 8; ++i) {
            unsigned long long m = runmin[i];
            #pragma unroll
            for (int j = 0; j < 8; ++j) {
                int e = e0 + tx * 8 + j;
                float d = wsq[e] - 2.0f * acc[i * 8 + j];
                unsigned long long key =
                    ((unsigned long long)f32_sortable(d) << 32) | (unsigned)e;
                m = (m < key) ? m : key;
            }
            runmin[i] = m;
        }
    }
    #pragma unroll
    for (int i = 0; i < 8; ++i) {
        unsigned long long kk = runmin[i];
        #pragma unroll
        for (int off = 8; off >= 1; off >>= 1) {
            unsigned long long o = __shfl_xor(kk, off, 16);
            kk = (kk < o) ? kk : o;
        }
        if (tx == 0) atomicMin(&best[n0 + ty * 8 + i], kk);
    }
}

__global__ __launch_bounds__(256) void extract_idx(const unsigned long long* __restrict__ best,
                                                   unsigned* __restrict__ idxarr) {
    int n = blockIdx.x * 256 + threadIdx.x;
    idxarr[n] = (unsigned)(best[n] & 0xFFFFFFFFull) & (NE - 1);
}

// K3: gather codebook rows, transpose-write z_q_st, loss partials, histogram, idx out.
__global__ __launch_bounds__(256) void gather_kernel(const float* __restrict__ z,
                                                     const float* __restrict__ w,
                                                     const unsigned* __restrict__ idxarr,
                                                     unsigned* __restrict__ counts,
                                                     float* __restrict__ loss,
                                                     float* __restrict__ out,
                                                     float* __restrict__ out_idx) {
    __shared__ int idx_s[64];
    __shared__ float wl[64 * 257];
    int tid = threadIdx.x;
    int n0 = blockIdx.x * 64;
    if (tid < 64) {
        int idx = (int)(idxarr[n0 + tid] & (NE - 1));
        idx_s[tid] = idx;
        out_idx[n0 + tid] = (float)idx;
        atomicAdd(&counts[idx], 1u);
    }
    __syncthreads();
    for (int i = 0; i < 64; ++i)
        wl[i * 257 + tid] = w[(size_t)idx_s[i] * EDIM + tid];
    __syncthreads();
    int tn = tid & 63, tc = tid >> 6;
    int bb_ = n0 >> 12, lhw0 = n0 & 4095;
    size_t zb = (size_t)bb_ * (EDIM * LHW) + lhw0 + tn;
    float accl = 0.f;
    for (int cc = 0; cc < 64; ++cc) {
        int c = tc * 64 + cc;
        float wv = wl[tn * 257 + c];
        size_t a = zb + (size_t)c * LHW;
        float zv = z[a];
        float diff = wv - zv;            // z_q - zc
        out[a] = zv + diff;              // replicate zc + (z_q - zc) rounding
        accl += diff * diff;
    }
    #pragma unroll
    for (int off = 32; off; off >>= 1) accl += __shfl_xor(accl, off, 64);
    if ((tid & 63) == 0) atomicAdd(loss, accl);
}

// K4: scalars
__global__ __launch_bounds__(256) void finalize_kernel(const unsigned* __restrict__ counts,
                                                       const float* __restrict__ loss,
                                                       float* __restrict__ out_scalars) {
    __shared__ float ss[4];
    __shared__ int uu[4];
    int tid = threadIdx.x;
    float s = 0.f;
    int uniq = 0;
    for (int i = tid; i < NE; i += 256) {
        unsigned c = counts[i];
        if (c > 0) {
            float p = (float)c * (1.0f / (float)NQ);
            s += p * logf(p + 1e-10f);
            uniq++;
        }
    }
    #pragma unroll
    for (int off = 32; off; off >>= 1) {
        s += __shfl_xor(s, off, 64);
        uniq += __shfl_xor(uniq, off, 64);
    }
    int wave = tid >> 6;
    if ((tid & 63) == 0) { ss[wave] = s; uu[wave] = uniq; }
    __syncthreads();
    if (tid == 0) {
        float st = ss[0] + ss[1] + ss[2] + ss[3];
        int ut = uu[0] + uu[1] + uu[2] + uu[3];
        out_scalars[0] = BETA * loss[0] * (1.0f / (float)(NQ * EDIM));  // loss
        out_scalars[1] = expf(-st);                                     // perplexity
        out_scalars[2] = (float)ut;                                     // unique
    }
}

extern "C" void kernel_launch(void* const* d_in, const int* in_sizes, int n_in,
                              void* d_out, int out_size, void* d_ws, size_t ws_size,
                              hipStream_t stream) {
    const float* z = (const float*)d_in[0];
    const float* w = (const float*)d_in[1];
    float* out = (float*)d_out;
    char* ws = (char*)d_ws;
    float* wsq = (float*)(ws + WS_WSQ);
    unsigned* counts = (unsigned*)(ws + WS_CNT);
    float* loss = (float*)(ws + WS_LOSS);
    unsigned* idxarr = (unsigned*)(ws + WS_IDX);
    unsigned long long* best = (unsigned long long*)(ws + WS_BEST);
    unsigned* Ap = (unsigned*)(ws + WS_APACK);
    unsigned* Bp = (unsigned*)(ws + WS_BPACK);

    int idx_off = out_size - NQ;
    int scal_off = idx_off - 3;
    float* out_idx = out + idx_off;
    float* out_scalars = out + scal_off;

    // z_q region of d_out doubles as the per-slice top-2 scratch (u32 keys,
    // written by dist_mfma, read by refine, overwritten by gather).
    unsigned* s1 = (unsigned*)out;

    if (ws_size >= (size_t)WS_NEED) {
        wsq_pack_w<<<NE / 4, 256, 0, stream>>>(w, wsq, Bp, counts, loss);
        pack_z<<<NQ / 64, 256, 0, stream>>>(z, Ap);
        dist_mfma<<<dim3(64, 64), 256, 0, stream>>>((const unsigned short*)Ap,
                                                    (const unsigned short*)Bp, wsq, s1);
        refine_kernel<<<NQ / 4, 256, 0, stream>>>(z, w, wsq, s1, idxarr);
    } else {
        hipMemsetAsync(counts, 0, NE * sizeof(unsigned), stream);
        hipMemsetAsync(loss, 0, sizeof(float), stream);
        wsq_kernel<<<NE / 4, 256, 0, stream>>>(w, wsq);
        hipMemsetAsync(best, 0xFF, NQ * sizeof(unsigned long long), stream);
        dist_fp32<<<dim3(4, 128), 256, 0, stream>>>(z, w, wsq, best);
        extract_idx<<<NQ / 256, 256, 0, stream>>>(best, idxarr);
    }

    gather_kernel<<<NQ / 64, 256, 0, stream>>>(z, w, idxarr, counts, loss, out, out_idx);
    finalize_kernel<<<1, 256, 0, stream>>>(counts, loss, out_scalars);
}

// Round 3
// 246.277 us; speedup vs baseline: 1.3820x; 1.0594x over previous
//
#include <hip/hip_runtime.h>

// Problem constants
#define NQ     16384       // 4*16*16*16 query vectors
#define EDIM   256
#define NE     8192
#define LHW    4096        // 16*16*16
#define BETA   0.25f

// ws layout (bytes) — K=256 bf16-hi packing.
#define WS_WSQ    0            // f32[NE]             32768
#define WS_CNT    32768        // u32[NE]             32768
#define WS_LOSS   65536        // f32 (+pad)          256
#define WS_IDX    65792        // u32[NQ]             65536
#define WS_BEST   131328       // u64[NQ] (fallback)  131072
#define WS_APACK  2359552      // ushort[NQ*256]      8388608
#define WS_BPACK  10748160     // ushort[NE*256]      4194304
#define WS_NEED   14942464

typedef __attribute__((ext_vector_type(8))) short bf16x8;
typedef __attribute__((ext_vector_type(4))) float f32x4;

__device__ __forceinline__ unsigned f32_sortable(float f) {
    unsigned b = __float_as_uint(f);
    return b ^ ((unsigned)((int)b >> 31) | 0x80000000u);   // 3 VALU ops
}
__device__ __forceinline__ unsigned short bf16_rn(float f) {
    unsigned u = __float_as_uint(f);
    return (unsigned short)((u + 0x7FFFu + ((u >> 16) & 1u)) >> 16);
}

// K1a (MFMA path): wsq + pack_w (bf16-hi only) fused; zeroes counts/loss.
__global__ __launch_bounds__(256) void wsq_pack_w(const float* __restrict__ w,
                                                  float* __restrict__ wsq,
                                                  unsigned* __restrict__ Bp32,
                                                  unsigned* __restrict__ counts,
                                                  float* __restrict__ loss) {
    int wave = threadIdx.x >> 6, lane = threadIdx.x & 63;
    int row = blockIdx.x * 4 + wave;
    if (blockIdx.x < 32) {
        counts[blockIdx.x * 256 + threadIdx.x] = 0u;
        if (blockIdx.x == 0 && threadIdx.x == 0) loss[0] = 0.f;
    }
    float4 v = *(const float4*)(w + (size_t)row * EDIM + lane * 4);
    double s = (double)v.x * v.x + (double)v.y * v.y +
               (double)v.z * v.z + (double)v.w * v.w;
    unsigned p0 = (unsigned)bf16_rn(v.x) | ((unsigned)bf16_rn(v.y) << 16);
    unsigned p1 = (unsigned)bf16_rn(v.z) | ((unsigned)bf16_rn(v.w) << 16);
    *(uint2*)(Bp32 + (size_t)row * 128 + lane * 2) = make_uint2(p0, p1);
    #pragma unroll
    for (int off = 32; off; off >>= 1) s += __shfl_xor(s, off, 64);
    if (lane == 0) wsq[row] = (float)s;
}

// K1b (fallback path): wsq only.
__global__ __launch_bounds__(256) void wsq_kernel(const float* __restrict__ w,
                                                  float* __restrict__ wsq) {
    int wave = threadIdx.x >> 6, lane = threadIdx.x & 63;
    int row = blockIdx.x * 4 + wave;
    float4 v = *(const float4*)(w + (size_t)row * EDIM + lane * 4);
    double s = (double)v.x * v.x + (double)v.y * v.y +
               (double)v.z * v.z + (double)v.w * v.w;
    #pragma unroll
    for (int off = 32; off; off >>= 1) s += __shfl_xor(s, off, 64);
    if (lane == 0) wsq[row] = (float)s;
}

// pack_z v2: 1024 threads/block (16 waves/CU vs 4 — the kernel was
// latency-bound at 1 block/CU with 64-deep serial load loops). Same 64-row
// LDS transpose tile, serial depth now 8x2 loads + 8 stores per thread.
__global__ __launch_bounds__(1024) void pack_z(const float* __restrict__ z,
                                               unsigned* __restrict__ Ap32) {
    __shared__ unsigned lds[64 * 129];
    int tid = threadIdx.x;
    int tn = tid & 63, tc = tid >> 6;       // tc in [0,16): 16 d-groups of 16
    int n0 = blockIdx.x * 64;
    int n = n0 + tn;
    int b = n >> 12, lhw = n & 4095;
    #pragma unroll
    for (int cc = 0; cc < 16; cc += 2) {
        int d = tc * 16 + cc;
        float v0 = z[((size_t)b * EDIM + d) * LHW + lhw];
        float v1 = z[((size_t)b * EDIM + d + 1) * LHW + lhw];
        lds[tn * 129 + (d >> 1)] =
            (unsigned)bf16_rn(v0) | ((unsigned)bf16_rn(v1) << 16);
    }
    __syncthreads();
    #pragma unroll
    for (int p = 0; p < 8; ++p) {
        int flat = p * 1024 + tid;          // 64 rows x 128 u32
        int row = flat >> 7, c = flat & 127;
        Ap32[(size_t)(n0 + row) * 128 + c] = lds[row * 129 + c];
    }
}

// K2-MFMA v12: identical pipeline to v11 (BK=64, r10 XOR swizzle, dbuf LDS,
// counted vmcnt, setprio). Epilogue trimmed: wq_off = wsq[e]+4096 makes every
// d' positive, so raw float bits ARE the sortable key — drops the 3-instr
// sortable transform per candidate (9 -> 5 VALU/candidate, 128 candidates).
// wsq itself stays unoffset so refine's exact fp32 path is unchanged.
__global__ __launch_bounds__(256, 2) void dist_mfma(const unsigned short* __restrict__ Ap,
                                                    const unsigned short* __restrict__ Bp,
                                                    const float* __restrict__ wsq,
                                                    unsigned* __restrict__ s1) {
    __shared__ __align__(16) unsigned short lds_b[2][128 * 64];   // 2 x 16 KB, swizzled
    int tid = threadIdx.x, lane = tid & 63, w = tid >> 6;
    int x = blockIdx.x, nt = blockIdx.y;
    int quad = lane >> 4, col = lane & 15;
    int rsel = lane >> 3, seg = lane & 7;   // glds: 8 rows x 8 segs of 16B per call

    const unsigned short* arow = Ap + (size_t)(nt * 256 + w * 64 + col) * 256;
    const unsigned short* Bbase = Bp + (size_t)(x * 128) * 256;

    f32x4 acc[4][8];
    #pragma unroll
    for (int i = 0; i < 4; ++i)
        #pragma unroll
        for (int j = 0; j < 8; ++j) acc[i][j] = (f32x4){0.f, 0.f, 0.f, 0.f};

    // stage B chunk kc into lds_b[bsel]: 16 calls of 1KB (4/wave), r10 swizzle.
    auto stage_chunk = [&](int kc, int bsel) {
        int k0s = kc * 64;
        #pragma unroll
        for (int p = 0; p < 4; ++p) {
            int c = w * 4 + p;
            const unsigned short* gb =
                Bbase + (size_t)(c * 8 + rsel) * 256 + k0s + ((seg ^ (rsel & 7)) * 8);
            __builtin_amdgcn_global_load_lds(
                (const __attribute__((address_space(1))) void*)gb,
                (__attribute__((address_space(3))) void*)(&lds_b[bsel][c * 512]),
                16, 0, 0);
        }
    };

    // prologue: stage chunk 0 into buffer 0 (no barrier needed; LDS unread yet)
    stage_chunk(0, 0);

    #pragma unroll
    for (int kcc = 0; kcc < 4; ++kcc) {
        int k0 = kcc * 64;
        int cur = kcc & 1;
        // A frags for this chunk: global -> VGPR (L2-resident tile), issued
        // before the next-chunk glds.
        bf16x8 af[4][2];
        #pragma unroll
        for (int i = 0; i < 4; ++i)
            #pragma unroll
            for (int h = 0; h < 2; ++h)
                af[i][h] = *(const bf16x8*)(arow + i * 16 * 256 + k0 + h * 32 + quad * 8);
        asm volatile("" ::: "memory");   // af above / glds below: fixes issue order
        if (kcc < 3) {
            stage_chunk(kcc + 1, cur ^ 1);
            // wait for MY glds of the CURRENT buffer (issued last iter):
            // newer vmem ops = af(8) + glds_next(4) = 12 (in-order retirement).
            asm volatile("s_waitcnt vmcnt(12)" ::: "memory");
        } else {
            // no prefetch issued: newer ops = af(8) only.
            asm volatile("s_waitcnt vmcnt(8)" ::: "memory");
        }
        __builtin_amdgcn_s_barrier();    // all waves' glds for cur buffer done
        asm volatile("" ::: "memory");   // ds_reads must not hoist above barrier
        __builtin_amdgcn_s_setprio(1);
        #pragma unroll
        for (int h = 0; h < 2; ++h) {
            bf16x8 bf[8];
            #pragma unroll
            for (int j = 0; j < 8; ++j)
                bf[j] = *(const bf16x8*)(&lds_b[cur][(j * 16 + col) * 64 +
                                         (((h * 4 + quad) ^ (col & 7)) * 8)]);
            #pragma unroll
            for (int i = 0; i < 4; ++i)
                #pragma unroll
                for (int j = 0; j < 8; ++j)
                    acc[i][j] = __builtin_amdgcn_mfma_f32_16x16x32_bf16(
                        af[i][h], bf[j], acc[i][j], 0, 0, 0);
        }
        __builtin_amdgcn_s_setprio(0);
        asm volatile("" ::: "memory");   // ds_reads/MFMA stay above the barrier
        if (kcc < 3) {
            // all waves done reading lds_b[cur] before next iter's glds
            // overwrite it (next iter stages chunk kcc+2 into buffer cur).
            __builtin_amdgcn_s_barrier();
            asm volatile("" ::: "memory");   // next glds must not hoist above
        }
    }

    // epilogue: d' = (wsq[e]+4096) - 2*dot  (always positive: wsq in ~[180,350],
    // |2*dot| <= 700 by Cauchy-Schwarz) -> raw float bits are u32-sortable.
    // key = (bits & ~0x7F) | e_local (one v_and_or_b32). Branchless top-2,
    // then cross-lane merge over 16 e-lanes.
    unsigned m1[4][4], m2[4][4];
    #pragma unroll
    for (int i = 0; i < 4; ++i)
        #pragma unroll
        for (int r = 0; r < 4; ++r) { m1[i][r] = 0xFFFFFFFFu; m2[i][r] = 0xFFFFFFFFu; }
    #pragma unroll
    for (int j = 0; j < 8; ++j) {
        int e = x * 128 + j * 16 + col;
        unsigned jc = (unsigned)(j * 16 + col);   // e_local, 7 bits
        float wq_off = wsq[e] + 4096.0f;
        #pragma unroll
        for (int i = 0; i < 4; ++i)
            #pragma unroll
            for (int r = 0; r < 4; ++r) {
                float d = fmaf(-2.0f, acc[i][j][r], wq_off);
                unsigned k = (__float_as_uint(d) & 0xFFFFFF80u) | jc;
                unsigned mx = (m1[i][r] > k) ? m1[i][r] : k;
                m1[i][r] = (m1[i][r] < k) ? m1[i][r] : k;
                m2[i][r] = (m2[i][r] < mx) ? m2[i][r] : mx;
            }
    }
    #pragma unroll
    for (int i = 0; i < 4; ++i)
        #pragma unroll
        for (int r = 0; r < 4; ++r) {
            unsigned a1 = m1[i][r], a2 = m2[i][r];
            #pragma unroll
            for (int off = 1; off < 16; off <<= 1) {
                unsigned b1 = __shfl_xor(a1, off, 64);
                unsigned b2 = __shfl_xor(a2, off, 64);
                unsigned lo1 = a1 < b1 ? a1 : b1;
                unsigned hi1 = a1 < b1 ? b1 : a1;
                unsigned lo2 = a2 < b2 ? a2 : b2;
                a1 = lo1;
                a2 = hi1 < lo2 ? hi1 : lo2;
            }
            if (col == 0) {
                int q = nt * 256 + w * 64 + i * 16 + quad * 4 + r;
                size_t o = (size_t)q * 128 + x * 2;
                s1[o] = a1; s1[o + 1] = a2;
            }
        }
}

// Refine (merge fused): per query, lane=slice holds its top-2 u32 keys
// (opaque monotone: raw positive-float bits, truncated, index in low 7);
// 3-step shfl-xor top-2 reduce within 8-lane groups -> 16 candidates
// (top-2 per 1024-e group); then exact fp32 distance for all 16,
// true argmin with first-index tiebreak. One wave per query.
__global__ __launch_bounds__(256) void refine_kernel(const float* __restrict__ z,
                                                     const float* __restrict__ w,
                                                     const float* __restrict__ wsq,
                                                     const unsigned* __restrict__ s1,
                                                     unsigned* __restrict__ idxarr) {
    int tid = threadIdx.x, lane = tid & 63, wv = tid >> 6;
    int q = blockIdx.x * 4 + wv;
    int b = q >> 12, lhw = q & 4095;
    // slice keys -> global u64 keys: (d_trunc << 13) | e_global
    uint2 kk2 = *(const uint2*)(s1 + (size_t)q * 128 + lane * 2);
    unsigned long long a1 =
        ((unsigned long long)(kk2.x >> 7) << 13) | (unsigned)(lane * 128 + (kk2.x & 127u));
    unsigned long long a2 =
        ((unsigned long long)(kk2.y >> 7) << 13) | (unsigned)(lane * 128 + (kk2.y & 127u));
    #pragma unroll
    for (int off = 1; off < 8; off <<= 1) {
        unsigned long long b1 = __shfl_xor(a1, off, 64);
        unsigned long long b2 = __shfl_xor(a2, off, 64);
        unsigned long long lo1 = a1 < b1 ? a1 : b1;
        unsigned long long hi1 = a1 < b1 ? b1 : a1;
        unsigned long long lo2 = a2 < b2 ? a2 : b2;
        a1 = lo1;
        a2 = hi1 < lo2 ? hi1 : lo2;
    }
    float zv[4];
    #pragma unroll
    for (int t = 0; t < 4; ++t)
        zv[t] = z[((size_t)b * EDIM + lane * 4 + t) * LHW + lhw];
    unsigned long long bestk = ~0ull;
    #pragma unroll
    for (int c = 0; c < 16; ++c) {
        int src = (c >> 1) * 8;
        unsigned long long kc = (c & 1) ? __shfl(a2, src, 64) : __shfl(a1, src, 64);
        unsigned e = (unsigned)(kc & (unsigned long long)(NE - 1));
        float4 wv4 = *(const float4*)(w + (size_t)e * EDIM + lane * 4);
        float p = zv[0] * wv4.x + zv[1] * wv4.y + zv[2] * wv4.z + zv[3] * wv4.w;
        #pragma unroll
        for (int off = 32; off; off >>= 1) p += __shfl_xor(p, off, 64);
        float d = wsq[e] - 2.0f * p;
        unsigned long long key = ((unsigned long long)f32_sortable(d) << 32) | e;
        if (key < bestk) bestk = key;
    }
    if (lane == 0) idxarr[q] = (unsigned)(bestk & 0xFFFFFFFFull);
}

// ---------- fallback fp32 path (used when ws_size < WS_NEED) ----------
__global__ __launch_bounds__(256, 2) void dist_fp32(const float* __restrict__ z,
                                                    const float* __restrict__ w,
                                                    const float* __restrict__ wsq,
                                                    unsigned long long* __restrict__ best) {
    __shared__ float lds_a[32 * 128];
    __shared__ float lds_b[32 * 132];
    int tid = threadIdx.x;
    int tx = tid & 15, ty = tid >> 4;
    int n0 = blockIdx.y * 128;
    int bb_ = n0 >> 12, lhw0 = n0 & 4095;
    const float* zb = z + (size_t)bb_ * (EDIM * LHW) + lhw0;
    int ebase = blockIdx.x * 2048;
    unsigned long long runmin[8];
    #pragma unroll
    for (int i = 0; i < 8; ++i) runmin[i] = ~0ull;
    float acc[64];
    for (int et = 0; et < 16; ++et) {
        int e0 = ebase + et * 128;
        #pragma unroll
        for (int i = 0; i < 64; ++i) acc[i] = 0.f;
        for (int kc = 0; kc < 8; ++kc) {
            int k0 = kc * 32;
            #pragma unroll
            for (int p = 0; p < 4; ++p) {
                int f = p * 256 + tid;
                int kk = f >> 5, nn4 = f & 31;
                float4 v = *(const float4*)(zb + (size_t)(k0 + kk) * LHW + nn4 * 4);
                *((float4*)(lds_a + kk * 128 + nn4 * 4)) = v;
            }
            #pragma unroll
            for (int p = 0; p < 4; ++p) {
                int f = p * 256 + tid;
                int ee = f >> 3, kk4 = f & 7;
                float4 v = *(const float4*)(w + (size_t)(e0 + ee) * EDIM + k0 + kk4 * 4);
                lds_b[(kk4 * 4 + 0) * 132 + ee] = v.x;
                lds_b[(kk4 * 4 + 1) * 132 + ee] = v.y;
                lds_b[(kk4 * 4 + 2) * 132 + ee] = v.z;
                lds_b[(kk4 * 4 + 3) * 132 + ee] = v.w;
            }
            __syncthreads();
            #pragma unroll
            for (int k = 0; k < 32; ++k) {
                float a[8], bv[8];
                *(float4*)(a)      = *(float4*)(lds_a + k * 128 + ty * 8);
                *(float4*)(a + 4)  = *(float4*)(lds_a + k * 128 + ty * 8 + 4);
                *(float4*)(bv)     = *(float4*)(lds_b + k * 132 + tx * 8);
                *(float4*)(bv + 4) = *(float4*)(lds_b + k * 132 + tx * 8 + 4);
                #pragma unroll
                for (int i = 0; i < 8; ++i)
                    #pragma unroll
                    for (int j = 0; j < 8; ++j)
                        acc[i * 8 + j] = fmaf(a[i], bv[j], acc[i * 8 + j]);
            }
            __syncthreads();
        }
        #pragma unroll
        for (int i = 0; i < 8; ++i) {
            unsigned long long m = runmin[i];
            #pragma unroll
            for (int j = 0; j < 8; ++j) {
                int e = e0 + tx * 8 + j;
                float d = wsq[e] - 2.0f * acc[i * 8 + j];
                unsigned long long key =
                    ((unsigned long long)f32_sortable(d) << 32) | (unsigned)e;
                m = (m < key) ? m : key;
            }
            runmin[i] = m;
        }
    }
    #pragma unroll
    for (int i = 0; i < 8; ++i) {
        unsigned long long kk = runmin[i];
        #pragma unroll
        for (int off = 8; off >= 1; off >>= 1) {
            unsigned long long o = __shfl_xor(kk, off, 16);
            kk = (kk < o) ? kk : o;
        }
        if (tx == 0) atomicMin(&best[n0 + ty * 8 + i], kk);
    }
}

__global__ __launch_bounds__(256) void extract_idx(const unsigned long long* __restrict__ best,
                                                   unsigned* __restrict__ idxarr) {
    int n = blockIdx.x * 256 + threadIdx.x;
    idxarr[n] = (unsigned)(best[n] & 0xFFFFFFFFull) & (NE - 1);
}

// K3 v2: 1024 threads/block (was 256 — latency-bound at 4 waves/CU with a
// 64-deep serial loop). Serial depth now 16; loss via LDS block-reduce so
// the single-address float atomics stay at 1/block.
__global__ __launch_bounds__(1024) void gather_kernel(const float* __restrict__ z,
                                                      const float* __restrict__ w,
                                                      const unsigned* __restrict__ idxarr,
                                                      unsigned* __restrict__ counts,
                                                      float* __restrict__ loss,
                                                      float* __restrict__ out,
                                                      float* __restrict__ out_idx) {
    __shared__ int idx_s[64];
    __shared__ float wl[64 * 257];
    __shared__ float lsum[16];
    int tid = threadIdx.x;
    int n0 = blockIdx.x * 64;
    if (tid < 64) {
        int idx = (int)(idxarr[n0 + tid] & (NE - 1));
        idx_s[tid] = idx;
        out_idx[n0 + tid] = (float)idx;
        atomicAdd(&counts[idx], 1u);
    }
    __syncthreads();
    {
        int r0 = tid >> 8, cl = tid & 255;       // 4 row-groups x 256 cols
        #pragma unroll
        for (int i = 0; i < 16; ++i)
            wl[(r0 + i * 4) * 257 + cl] = w[(size_t)idx_s[r0 + i * 4] * EDIM + cl];
    }
    __syncthreads();
    int tn = tid & 63, tc = tid >> 6;            // tc in [0,16): 16 d-groups of 16
    int bb_ = n0 >> 12, lhw0 = n0 & 4095;
    size_t zb = (size_t)bb_ * (EDIM * LHW) + lhw0 + tn;
    float accl = 0.f;
    #pragma unroll
    for (int cc = 0; cc < 16; ++cc) {
        int c = tc * 16 + cc;
        float wv = wl[tn * 257 + c];
        size_t a = zb + (size_t)c * LHW;
        float zv = z[a];
        float diff = wv - zv;            // z_q - zc
        out[a] = zv + diff;              // replicate zc + (z_q - zc) rounding
        accl += diff * diff;
    }
    #pragma unroll
    for (int off = 32; off; off >>= 1) accl += __shfl_xor(accl, off, 64);
    if ((tid & 63) == 0) lsum[tid >> 6] = accl;
    __syncthreads();
    if (tid < 16) {
        float v = lsum[tid];
        v += __shfl_xor(v, 8, 16);
        v += __shfl_xor(v, 4, 16);
        v += __shfl_xor(v, 2, 16);
        v += __shfl_xor(v, 1, 16);
        if (tid == 0) atomicAdd(loss, v);
    }
}

// K4: scalars
__global__ __launch_bounds__(256) void finalize_kernel(const unsigned* __restrict__ counts,
                                                       const float* __restrict__ loss,
                                                       float* __restrict__ out_scalars) {
    __shared__ float ss[4];
    __shared__ int uu[4];
    int tid = threadIdx.x;
    float s = 0.f;
    int uniq = 0;
    for (int i = tid; i < NE; i += 256) {
        unsigned c = counts[i];
        if (c > 0) {
            float p = (float)c * (1.0f / (float)NQ);
            s += p * logf(p + 1e-10f);
            uniq++;
        }
    }
    #pragma unroll
    for (int off = 32; off; off >>= 1) {
        s += __shfl_xor(s, off, 64);
        uniq += __shfl_xor(uniq, off, 64);
    }
    int wave = tid >> 6;
    if ((tid & 63) == 0) { ss[wave] = s; uu[wave] = uniq; }
    __syncthreads();
    if (tid == 0) {
        float st = ss[0] + ss[1] + ss[2] + ss[3];
        int ut = uu[0] + uu[1] + uu[2] + uu[3];
        out_scalars[0] = BETA * loss[0] * (1.0f / (float)(NQ * EDIM));  // loss
        out_scalars[1] = expf(-st);                                     // perplexity
        out_scalars[2] = (float)ut;                                     // unique
    }
}

extern "C" void kernel_launch(void* const* d_in, const int* in_sizes, int n_in,
                              void* d_out, int out_size, void* d_ws, size_t ws_size,
                              hipStream_t stream) {
    const float* z = (const float*)d_in[0];
    const float* w = (const float*)d_in[1];
    float* out = (float*)d_out;
    char* ws = (char*)d_ws;
    float* wsq = (float*)(ws + WS_WSQ);
    unsigned* counts = (unsigned*)(ws + WS_CNT);
    float* loss = (float*)(ws + WS_LOSS);
    unsigned* idxarr = (unsigned*)(ws + WS_IDX);
    unsigned long long* best = (unsigned long long*)(ws + WS_BEST);
    unsigned* Ap = (unsigned*)(ws + WS_APACK);
    unsigned* Bp = (unsigned*)(ws + WS_BPACK);

    int idx_off = out_size - NQ;
    int scal_off = idx_off - 3;
    float* out_idx = out + idx_off;
    float* out_scalars = out + scal_off;

    // z_q region of d_out doubles as the per-slice top-2 scratch (u32 keys,
    // written by dist_mfma, read by refine, overwritten by gather).
    unsigned* s1 = (unsigned*)out;

    if (ws_size >= (size_t)WS_NEED) {
        wsq_pack_w<<<NE / 4, 256, 0, stream>>>(w, wsq, Bp, counts, loss);
        pack_z<<<NQ / 64, 1024, 0, stream>>>(z, Ap);
        dist_mfma<<<dim3(64, 64), 256, 0, stream>>>((const unsigned short*)Ap,
                                                    (const unsigned short*)Bp, wsq, s1);
        refine_kernel<<<NQ / 4, 256, 0, stream>>>(z, w, wsq, s1, idxarr);
    } else {
        hipMemsetAsync(counts, 0, NE * sizeof(unsigned), stream);
        hipMemsetAsync(loss, 0, sizeof(float), stream);
        wsq_kernel<<<NE / 4, 256, 0, stream>>>(w, wsq);
        hipMemsetAsync(best, 0xFF, NQ * sizeof(unsigned long long), stream);
        dist_fp32<<<dim3(4, 128), 256, 0, stream>>>(z, w, wsq, best);
        extract_idx<<<NQ / 256, 256, 0, stream>>>(best, idxarr);
    }

    gather_kernel<<<NQ / 64, 1024, 0, stream>>>(z, w, idxarr, counts, loss, out, out_idx);
    finalize_kernel<<<1, 256, 0, stream>>>(counts, loss, out_scalars);
}

// Round 4
// 233.801 us; speedup vs baseline: 1.4557x; 1.0534x over previous
//
#include <hip/hip_runtime.h>

// Problem constants
#define NQ     16384       // 4*16*16*16 query vectors
#define EDIM   256
#define NE     8192
#define LHW    4096        // 16*16*16
#define BETA   0.25f

// ws layout (bytes) — K=256 bf16-hi packing.
#define WS_WSQ    0            // f32[NE]             32768
#define WS_CNT    32768        // u32[NE]             32768
#define WS_LOSS   65536        // f32 (+pad)          256
#define WS_IDX    65792        // u32[NQ]             65536
#define WS_BEST   131328       // u64[NQ] (fallback)  131072
#define WS_APACK  2359552      // ushort[NQ*256]      8388608
#define WS_BPACK  10748160     // ushort[NE*256]      4194304
#define WS_NEED   14942464

typedef __attribute__((ext_vector_type(8))) short bf16x8;
typedef __attribute__((ext_vector_type(4))) float f32x4;

__device__ __forceinline__ unsigned f32_sortable(float f) {
    unsigned b = __float_as_uint(f);
    return b ^ ((unsigned)((int)b >> 31) | 0x80000000u);   // 3 VALU ops
}
__device__ __forceinline__ unsigned short bf16_rn(float f) {
    unsigned u = __float_as_uint(f);
    return (unsigned short)((u + 0x7FFFu + ((u >> 16) & 1u)) >> 16);
}

// K1a (MFMA path): wsq + pack_w (bf16-hi only) fused; zeroes counts/loss.
__global__ __launch_bounds__(256) void wsq_pack_w(const float* __restrict__ w,
                                                  float* __restrict__ wsq,
                                                  unsigned* __restrict__ Bp32,
                                                  unsigned* __restrict__ counts,
                                                  float* __restrict__ loss) {
    int wave = threadIdx.x >> 6, lane = threadIdx.x & 63;
    int row = blockIdx.x * 4 + wave;
    if (blockIdx.x < 32) {
        counts[blockIdx.x * 256 + threadIdx.x] = 0u;
        if (blockIdx.x == 0 && threadIdx.x == 0) loss[0] = 0.f;
    }
    float4 v = *(const float4*)(w + (size_t)row * EDIM + lane * 4);
    double s = (double)v.x * v.x + (double)v.y * v.y +
               (double)v.z * v.z + (double)v.w * v.w;
    unsigned p0 = (unsigned)bf16_rn(v.x) | ((unsigned)bf16_rn(v.y) << 16);
    unsigned p1 = (unsigned)bf16_rn(v.z) | ((unsigned)bf16_rn(v.w) << 16);
    *(uint2*)(Bp32 + (size_t)row * 128 + lane * 2) = make_uint2(p0, p1);
    #pragma unroll
    for (int off = 32; off; off >>= 1) s += __shfl_xor(s, off, 64);
    if (lane == 0) wsq[row] = (float)s;
}

// K1b (fallback path): wsq only.
__global__ __launch_bounds__(256) void wsq_kernel(const float* __restrict__ w,
                                                  float* __restrict__ wsq) {
    int wave = threadIdx.x >> 6, lane = threadIdx.x & 63;
    int row = blockIdx.x * 4 + wave;
    float4 v = *(const float4*)(w + (size_t)row * EDIM + lane * 4);
    double s = (double)v.x * v.x + (double)v.y * v.y +
               (double)v.z * v.z + (double)v.w * v.w;
    #pragma unroll
    for (int off = 32; off; off >>= 1) s += __shfl_xor(s, off, 64);
    if (lane == 0) wsq[row] = (float)s;
}

// pack_z: 1024 threads/block; 64-row LDS transpose tile.
__global__ __launch_bounds__(1024) void pack_z(const float* __restrict__ z,
                                               unsigned* __restrict__ Ap32) {
    __shared__ unsigned lds[64 * 129];
    int tid = threadIdx.x;
    int tn = tid & 63, tc = tid >> 6;       // tc in [0,16): 16 d-groups of 16
    int n0 = blockIdx.x * 64;
    int n = n0 + tn;
    int b = n >> 12, lhw = n & 4095;
    #pragma unroll
    for (int cc = 0; cc < 16; cc += 2) {
        int d = tc * 16 + cc;
        float v0 = z[((size_t)b * EDIM + d) * LHW + lhw];
        float v1 = z[((size_t)b * EDIM + d + 1) * LHW + lhw];
        lds[tn * 129 + (d >> 1)] =
            (unsigned)bf16_rn(v0) | ((unsigned)bf16_rn(v1) << 16);
    }
    __syncthreads();
    #pragma unroll
    for (int p = 0; p < 8; ++p) {
        int flat = p * 1024 + tid;          // 64 rows x 128 u32
        int row = flat >> 7, c = flat & 127;
        Ap32[(size_t)(n0 + row) * 128 + c] = lds[row * 129 + c];
    }
}

// K2-MFMA v13: BARRIER-FREE K-loop. The whole 128e x 256k B-tile (64 KB) is
// staged to LDS once (16 glds/thread), then ONE counted vmcnt(8) + ONE
// s_barrier; the 4-chunk MFMA loop has no syncs at all — LDS is written once,
// read many. The 8 resident waves/CU free-run staggered, so af-load and
// ds_read latency hide across waves (v12's per-chunk lockstep barriers were
// the ~70% stall). Same r10 XOR swizzle (0 conflicts), same epilogue as v12.
__global__ __launch_bounds__(256, 2) void dist_mfma(const unsigned short* __restrict__ Ap,
                                                    const unsigned short* __restrict__ Bp,
                                                    const float* __restrict__ wsq,
                                                    unsigned* __restrict__ s1) {
    __shared__ __align__(16) unsigned short lds_b[4][128 * 64];   // 64 KB total
    int tid = threadIdx.x, lane = tid & 63, w = tid >> 6;
    int x = blockIdx.x, nt = blockIdx.y;
    int quad = lane >> 4, col = lane & 15;
    int rsel = lane >> 3, seg = lane & 7;   // glds: 8 rows x 8 segs of 16B per call

    const unsigned short* arow = Ap + (size_t)(nt * 256 + w * 64 + col) * 256;
    const unsigned short* Bbase = Bp + (size_t)(x * 128) * 256;

    f32x4 acc[4][8];
    #pragma unroll
    for (int i = 0; i < 4; ++i)
        #pragma unroll
        for (int j = 0; j < 8; ++j) acc[i][j] = (f32x4){0.f, 0.f, 0.f, 0.f};

    // stage ALL of B: 4 chunks x 16 KB, 16 glds calls/thread, r10 swizzle.
    #pragma unroll
    for (int kc = 0; kc < 4; ++kc) {
        int k0s = kc * 64;
        #pragma unroll
        for (int p = 0; p < 4; ++p) {
            int c = w * 4 + p;
            const unsigned short* gb =
                Bbase + (size_t)(c * 8 + rsel) * 256 + k0s + ((seg ^ (rsel & 7)) * 8);
            __builtin_amdgcn_global_load_lds(
                (const __attribute__((address_space(1))) void*)gb,
                (__attribute__((address_space(3))) void*)(&lds_b[kc][c * 512]),
                16, 0, 0);
        }
    }
    asm volatile("" ::: "memory");   // glds above / af below: pins issue order
    // af chunk 0 (global -> VGPR, L2-resident)
    bf16x8 af[4][2];
    #pragma unroll
    for (int i = 0; i < 4; ++i)
        #pragma unroll
        for (int h = 0; h < 2; ++h)
            af[i][h] = *(const bf16x8*)(arow + i * 16 * 256 + h * 32 + quad * 8);
    asm volatile("" ::: "memory");   // af must stay above the counted wait
    // 8 af loads are the only vmem ops newer than the 16 glds -> vmcnt(8)
    // guarantees ALL glds retired (in-order), af still in flight.
    asm volatile("s_waitcnt vmcnt(8)" ::: "memory");
    __builtin_amdgcn_s_barrier();    // the ONLY barrier: B fully staged
    asm volatile("" ::: "memory");

    #pragma unroll
    for (int kcc = 0; kcc < 4; ++kcc) {
        if (kcc) {
            int k0 = kcc * 64;       // reload af for this chunk (single-buffered;
            #pragma unroll           // compiler handles WAR vs prior MFMAs)
            for (int i = 0; i < 4; ++i)
                #pragma unroll
                for (int h = 0; h < 2; ++h)
                    af[i][h] = *(const bf16x8*)(arow + i * 16 * 256 + k0 + h * 32 + quad * 8);
        }
        __builtin_amdgcn_s_setprio(1);
        #pragma unroll
        for (int h = 0; h < 2; ++h) {
            bf16x8 bf[8];
            #pragma unroll
            for (int j = 0; j < 8; ++j)
                bf[j] = *(const bf16x8*)(&lds_b[kcc][(j * 16 + col) * 64 +
                                         (((h * 4 + quad) ^ (col & 7)) * 8)]);
            #pragma unroll
            for (int i = 0; i < 4; ++i)
                #pragma unroll
                for (int j = 0; j < 8; ++j)
                    acc[i][j] = __builtin_amdgcn_mfma_f32_16x16x32_bf16(
                        af[i][h], bf[j], acc[i][j], 0, 0, 0);
        }
        __builtin_amdgcn_s_setprio(0);
    }

    // epilogue: d' = (wsq[e]+4096) - 2*dot  (always positive) -> raw float
    // bits are u32-sortable. key = (bits & ~0x7F) | e_local. Branchless top-2,
    // then cross-lane merge over 16 e-lanes.
    unsigned m1[4][4], m2[4][4];
    #pragma unroll
    for (int i = 0; i < 4; ++i)
        #pragma unroll
        for (int r = 0; r < 4; ++r) { m1[i][r] = 0xFFFFFFFFu; m2[i][r] = 0xFFFFFFFFu; }
    #pragma unroll
    for (int j = 0; j < 8; ++j) {
        int e = x * 128 + j * 16 + col;
        unsigned jc = (unsigned)(j * 16 + col);   // e_local, 7 bits
        float wq_off = wsq[e] + 4096.0f;
        #pragma unroll
        for (int i = 0; i < 4; ++i)
            #pragma unroll
            for (int r = 0; r < 4; ++r) {
                float d = fmaf(-2.0f, acc[i][j][r], wq_off);
                unsigned k = (__float_as_uint(d) & 0xFFFFFF80u) | jc;
                unsigned mx = (m1[i][r] > k) ? m1[i][r] : k;
                m1[i][r] = (m1[i][r] < k) ? m1[i][r] : k;
                m2[i][r] = (m2[i][r] < mx) ? m2[i][r] : mx;
            }
    }
    #pragma unroll
    for (int i = 0; i < 4; ++i)
        #pragma unroll
        for (int r = 0; r < 4; ++r) {
            unsigned a1 = m1[i][r], a2 = m2[i][r];
            #pragma unroll
            for (int off = 1; off < 16; off <<= 1) {
                unsigned b1 = __shfl_xor(a1, off, 64);
                unsigned b2 = __shfl_xor(a2, off, 64);
                unsigned lo1 = a1 < b1 ? a1 : b1;
                unsigned hi1 = a1 < b1 ? b1 : a1;
                unsigned lo2 = a2 < b2 ? a2 : b2;
                a1 = lo1;
                a2 = hi1 < lo2 ? hi1 : lo2;
            }
            if (col == 0) {
                int q = nt * 256 + w * 64 + i * 16 + quad * 4 + r;
                size_t o = (size_t)q * 128 + x * 2;
                s1[o] = a1; s1[o + 1] = a2;
            }
        }
}

// Refine v2: per block (4 consecutive q = 4 consecutive lhw, same b), the z
// column-gather is cooperatively staged: 256 threads load one float4 each
// (16B segments, 4x fewer scattered transactions than per-wave dword gathers),
// transposed through 4KB LDS; each wave then reads its q's row conflict-free.
// Candidate merge + exact fp32 recompute unchanged.
__global__ __launch_bounds__(256) void refine_kernel(const float* __restrict__ z,
                                                     const float* __restrict__ w,
                                                     const float* __restrict__ wsq,
                                                     const unsigned* __restrict__ s1,
                                                     unsigned* __restrict__ idxarr) {
    __shared__ float lds_z[4][260];
    int tid = threadIdx.x, lane = tid & 63, wv = tid >> 6;
    int q0 = blockIdx.x * 4;
    int q = q0 + wv;
    int b = q0 >> 12, lhw0 = q0 & 4095;     // block never crosses a b boundary
    {
        float4 zc = *(const float4*)(z + ((size_t)b * EDIM + tid) * LHW + lhw0);
        lds_z[0][tid] = zc.x; lds_z[1][tid] = zc.y;
        lds_z[2][tid] = zc.z; lds_z[3][tid] = zc.w;
    }
    // slice keys -> global u64 keys: (d_trunc << 13) | e_global
    uint2 kk2 = *(const uint2*)(s1 + (size_t)q * 128 + lane * 2);
    unsigned long long a1 =
        ((unsigned long long)(kk2.x >> 7) << 13) | (unsigned)(lane * 128 + (kk2.x & 127u));
    unsigned long long a2 =
        ((unsigned long long)(kk2.y >> 7) << 13) | (unsigned)(lane * 128 + (kk2.y & 127u));
    #pragma unroll
    for (int off = 1; off < 8; off <<= 1) {
        unsigned long long b1 = __shfl_xor(a1, off, 64);
        unsigned long long b2 = __shfl_xor(a2, off, 64);
        unsigned long long lo1 = a1 < b1 ? a1 : b1;
        unsigned long long hi1 = a1 < b1 ? b1 : a1;
        unsigned long long lo2 = a2 < b2 ? a2 : b2;
        a1 = lo1;
        a2 = hi1 < lo2 ? hi1 : lo2;
    }
    __syncthreads();
    float zv[4];
    #pragma unroll
    for (int t = 0; t < 4; ++t)
        zv[t] = lds_z[wv][lane * 4 + t];
    unsigned long long bestk = ~0ull;
    #pragma unroll
    for (int c = 0; c < 16; ++c) {
        int src = (c >> 1) * 8;
        unsigned long long kc = (c & 1) ? __shfl(a2, src, 64) : __shfl(a1, src, 64);
        unsigned e = (unsigned)(kc & (unsigned long long)(NE - 1));
        float4 wv4 = *(const float4*)(w + (size_t)e * EDIM + lane * 4);
        float p = zv[0] * wv4.x + zv[1] * wv4.y + zv[2] * wv4.z + zv[3] * wv4.w;
        #pragma unroll
        for (int off = 32; off; off >>= 1) p += __shfl_xor(p, off, 64);
        float d = wsq[e] - 2.0f * p;
        unsigned long long key = ((unsigned long long)f32_sortable(d) << 32) | e;
        if (key < bestk) bestk = key;
    }
    if (lane == 0) idxarr[q] = (unsigned)(bestk & 0xFFFFFFFFull);
}

// ---------- fallback fp32 path (used when ws_size < WS_NEED) ----------
__global__ __launch_bounds__(256, 2) void dist_fp32(const float* __restrict__ z,
                                                    const float* __restrict__ w,
                                                    const float* __restrict__ wsq,
                                                    unsigned long long* __restrict__ best) {
    __shared__ float lds_a[32 * 128];
    __shared__ float lds_b[32 * 132];
    int tid = threadIdx.x;
    int tx = tid & 15, ty = tid >> 4;
    int n0 = blockIdx.y * 128;
    int bb_ = n0 >> 12, lhw0 = n0 & 4095;
    const float* zb = z + (size_t)bb_ * (EDIM * LHW) + lhw0;
    int ebase = blockIdx.x * 2048;
    unsigned long long runmin[8];
    #pragma unroll
    for (int i = 0; i < 8; ++i) runmin[i] = ~0ull;
    float acc[64];
    for (int et = 0; et < 16; ++et) {
        int e0 = ebase + et * 128;
        #pragma unroll
        for (int i = 0; i < 64; ++i) acc[i] = 0.f;
        for (int kc = 0; kc < 8; ++kc) {
            int k0 = kc * 32;
            #pragma unroll
            for (int p = 0; p < 4; ++p) {
                int f = p * 256 + tid;
                int kk = f >> 5, nn4 = f & 31;
                float4 v = *(const float4*)(zb + (size_t)(k0 + kk) * LHW + nn4 * 4);
                *((float4*)(lds_a + kk * 128 + nn4 * 4)) = v;
            }
            #pragma unroll
            for (int p = 0; p < 4; ++p) {
                int f = p * 256 + tid;
                int ee = f >> 3, kk4 = f & 7;
                float4 v = *(const float4*)(w + (size_t)(e0 + ee) * EDIM + k0 + kk4 * 4);
                lds_b[(kk4 * 4 + 0) * 132 + ee] = v.x;
                lds_b[(kk4 * 4 + 1) * 132 + ee] = v.y;
                lds_b[(kk4 * 4 + 2) * 132 + ee] = v.z;
                lds_b[(kk4 * 4 + 3) * 132 + ee] = v.w;
            }
            __syncthreads();
            #pragma unroll
            for (int k = 0; k < 32; ++k) {
                float a[8], bv[8];
                *(float4*)(a)      = *(float4*)(lds_a + k * 128 + ty * 8);
                *(float4*)(a + 4)  = *(float4*)(lds_a + k * 128 + ty * 8 + 4);
                *(float4*)(bv)     = *(float4*)(lds_b + k * 132 + tx * 8);
                *(float4*)(bv + 4) = *(float4*)(lds_b + k * 132 + tx * 8 + 4);
                #pragma unroll
                for (int i = 0; i < 8; ++i)
                    #pragma unroll
                    for (int j = 0; j < 8; ++j)
                        acc[i * 8 + j] = fmaf(a[i], bv[j], acc[i * 8 + j]);
            }
            __syncthreads();
        }
        #pragma unroll
        for (int i = 0; i < 8; ++i) {
            unsigned long long m = runmin[i];
            #pragma unroll
            for (int j = 0; j < 8; ++j) {
                int e = e0 + tx * 8 + j;
                float d = wsq[e] - 2.0f * acc[i * 8 + j];
                unsigned long long key =
                    ((unsigned long long)f32_sortable(d) << 32) | (unsigned)e;
                m = (m < key) ? m : key;
            }
            runmin[i] = m;
        }
    }
    #pragma unroll
    for (int i = 0; i < 8; ++i) {
        unsigned long long kk = runmin[i];
        #pragma unroll
        for (int off = 8; off >= 1; off >>= 1) {
            unsigned long long o = __shfl_xor(kk, off, 16);
            kk = (kk < o) ? kk : o;
        }
        if (tx == 0) atomicMin(&best[n0 + ty * 8 + i], kk);
    }
}

__global__ __launch_bounds__(256) void extract_idx(const unsigned long long* __restrict__ best,
                                                   unsigned* __restrict__ idxarr) {
    int n = blockIdx.x * 256 + threadIdx.x;
    idxarr[n] = (unsigned)(best[n] & 0xFFFFFFFFull) & (NE - 1);
}

// K3: 1024 threads/block; loss via LDS block-reduce.
__global__ __launch_bounds__(1024) void gather_kernel(const float* __restrict__ z,
                                                      const float* __restrict__ w,
                                                      const unsigned* __restrict__ idxarr,
                                                      unsigned* __restrict__ counts,
                                                      float* __restrict__ loss,
                                                      float* __restrict__ out,
                                                      float* __restrict__ out_idx) {
    __shared__ int idx_s[64];
    __shared__ float wl[64 * 257];
    __shared__ float lsum[16];
    int tid = threadIdx.x;
    int n0 = blockIdx.x * 64;
    if (tid < 64) {
        int idx = (int)(idxarr[n0 + tid] & (NE - 1));
        idx_s[tid] = idx;
        out_idx[n0 + tid] = (float)idx;
        atomicAdd(&counts[idx], 1u);
    }
    __syncthreads();
    {
        int r0 = tid >> 8, cl = tid & 255;       // 4 row-groups x 256 cols
        #pragma unroll
        for (int i = 0; i < 16; ++i)
            wl[(r0 + i * 4) * 257 + cl] = w[(size_t)idx_s[r0 + i * 4] * EDIM + cl];
    }
    __syncthreads();
    int tn = tid & 63, tc = tid >> 6;            // tc in [0,16): 16 d-groups of 16
    int bb_ = n0 >> 12, lhw0 = n0 & 4095;
    size_t zb = (size_t)bb_ * (EDIM * LHW) + lhw0 + tn;
    float accl = 0.f;
    #pragma unroll
    for (int cc = 0; cc < 16; ++cc) {
        int c = tc * 16 + cc;
        float wv = wl[tn * 257 + c];
        size_t a = zb + (size_t)c * LHW;
        float zv = z[a];
        float diff = wv - zv;            // z_q - zc
        out[a] = zv + diff;              // replicate zc + (z_q - zc) rounding
        accl += diff * diff;
    }
    #pragma unroll
    for (int off = 32; off; off >>= 1) accl += __shfl_xor(accl, off, 64);
    if ((tid & 63) == 0) lsum[tid >> 6] = accl;
    __syncthreads();
    if (tid < 16) {
        float v = lsum[tid];
        v += __shfl_xor(v, 8, 16);
        v += __shfl_xor(v, 4, 16);
        v += __shfl_xor(v, 2, 16);
        v += __shfl_xor(v, 1, 16);
        if (tid == 0) atomicAdd(loss, v);
    }
}

// K4: scalars
__global__ __launch_bounds__(256) void finalize_kernel(const unsigned* __restrict__ counts,
                                                       const float* __restrict__ loss,
                                                       float* __restrict__ out_scalars) {
    __shared__ float ss[4];
    __shared__ int uu[4];
    int tid = threadIdx.x;
    float s = 0.f;
    int uniq = 0;
    for (int i = tid; i < NE; i += 256) {
        unsigned c = counts[i];
        if (c > 0) {
            float p = (float)c * (1.0f / (float)NQ);
            s += p * logf(p + 1e-10f);
            uniq++;
        }
    }
    #pragma unroll
    for (int off = 32; off; off >>= 1) {
        s += __shfl_xor(s, off, 64);
        uniq += __shfl_xor(uniq, off, 64);
    }
    int wave = tid >> 6;
    if ((tid & 63) == 0) { ss[wave] = s; uu[wave] = uniq; }
    __syncthreads();
    if (tid == 0) {
        float st = ss[0] + ss[1] + ss[2] + ss[3];
        int ut = uu[0] + uu[1] + uu[2] + uu[3];
        out_scalars[0] = BETA * loss[0] * (1.0f / (float)(NQ * EDIM));  // loss
        out_scalars[1] = expf(-st);                                     // perplexity
        out_scalars[2] = (float)ut;                                     // unique
    }
}

extern "C" void kernel_launch(void* const* d_in, const int* in_sizes, int n_in,
                              void* d_out, int out_size, void* d_ws, size_t ws_size,
                              hipStream_t stream) {
    const float* z = (const float*)d_in[0];
    const float* w = (const float*)d_in[1];
    float* out = (float*)d_out;
    char* ws = (char*)d_ws;
    float* wsq = (float*)(ws + WS_WSQ);
    unsigned* counts = (unsigned*)(ws + WS_CNT);
    float* loss = (float*)(ws + WS_LOSS);
    unsigned* idxarr = (unsigned*)(ws + WS_IDX);
    unsigned long long* best = (unsigned long long*)(ws + WS_BEST);
    unsigned* Ap = (unsigned*)(ws + WS_APACK);
    unsigned* Bp = (unsigned*)(ws + WS_BPACK);

    int idx_off = out_size - NQ;
    int scal_off = idx_off - 3;
    float* out_idx = out + idx_off;
    float* out_scalars = out + scal_off;

    // z_q region of d_out doubles as the per-slice top-2 scratch (u32 keys,
    // written by dist_mfma, read by refine, overwritten by gather).
    unsigned* s1 = (unsigned*)out;

    if (ws_size >= (size_t)WS_NEED) {
        wsq_pack_w<<<NE / 4, 256, 0, stream>>>(w, wsq, Bp, counts, loss);
        pack_z<<<NQ / 64, 1024, 0, stream>>>(z, Ap);
        dist_mfma<<<dim3(64, 64), 256, 0, stream>>>((const unsigned short*)Ap,
                                                    (const unsigned short*)Bp, wsq, s1);
        refine_kernel<<<NQ / 4, 256, 0, stream>>>(z, w, wsq, s1, idxarr);
    } else {
        hipMemsetAsync(counts, 0, NE * sizeof(unsigned), stream);
        hipMemsetAsync(loss, 0, sizeof(float), stream);
        wsq_kernel<<<NE / 4, 256, 0, stream>>>(w, wsq);
        hipMemsetAsync(best, 0xFF, NQ * sizeof(unsigned long long), stream);
        dist_fp32<<<dim3(4, 128), 256, 0, stream>>>(z, w, wsq, best);
        extract_idx<<<NQ / 256, 256, 0, stream>>>(best, idxarr);
    }

    gather_kernel<<<NQ / 64, 1024, 0, stream>>>(z, w, idxarr, counts, loss, out, out_idx);
    finalize_kernel<<<1, 256, 0, stream>>>(counts, loss, out_scalars);
}